// Round 3
// baseline (649.468 us; speedup 1.0000x reference)
//
#include <hip/hip_runtime.h>
#include <hip/hip_bf16.h>

#define M_NODES 100000
#define N_EDGES 1600000
#define K_IN 512
#define N_OUT 256

typedef short bf16x8 __attribute__((ext_vector_type(8)));
typedef float f32x4 __attribute__((ext_vector_type(4)));

__device__ inline unsigned short f2bf_u(float f) {
  union { float f; unsigned u; } x; x.f = f;
  unsigned r = x.u + 0x7FFFu + ((x.u >> 16) & 1u);
  return (unsigned short)(r >> 16);
}
__device__ inline float bfu2f(unsigned short h) {
  union { unsigned u; float f; } x; x.u = ((unsigned)h) << 16;
  return x.f;
}
// tanh(x) = sign(x) * (1-z)/(1+z), z = exp(-2|x|). ~7 VALU + 1 trans.
__device__ inline float fast_tanh(float x) {
  float ax = __builtin_fabsf(x);
  float z = __expf(-2.0f * ax);
  float t = (1.0f - z) * __builtin_amdgcn_rcpf(1.0f + z);
  return __builtin_copysignf(t, x);
}

// weight [512][256] f32 -> Wt bf16 [256][512] (transposed: B-frag k-contiguous)
__global__ void prep_w_kernel(const float* __restrict__ w, short* __restrict__ wt) {
  int idx = blockIdx.x * 256 + threadIdx.x;   // 131072 total
  int k = idx >> 8, n = idx & 255;
  wt[n * K_IN + k] = (short)f2bf_u(w[idx]);
}

// row_ptr[r] = lower_bound(row, r) over sorted row[] (COO -> CSR)
__global__ void build_rp_kernel(const int* __restrict__ row, int* __restrict__ rp) {
  int r = blockIdx.x * 256 + threadIdx.x;
  if (r > M_NODES) return;
  int lo = 0, hi = N_EDGES;
  while (lo < hi) {
    int mid = (lo + hi) >> 1;
    if (row[mid] < r) lo = mid + 1; else hi = mid;
  }
  rp[r] = lo;
}

// H = bf16(tanh(A @ W)). A fp32 [M,512], Wt bf16 [256][512] (L2-resident).
// BARRIER-FREE, LDS-FREE: each wave independently owns 32 rows x 256 cols
// (acc[2][16] f32x4 = 128 VGPR). The MFMA A-fragment for lane (quad,l16) is
// A[m*16+l16][quad*8 .. +8] = 8 consecutive floats -> loaded DIRECTLY from
// global as 2 coalesced float4 (16 rows x 128B contiguous segments per
// instruction), converted to bf16 in-register. B-fragments load straight
// from L2-resident Wt (all waves read the same 16KB/k-step -> L1/L2 hits).
// No __syncthreads, no LDS: an A-latency stall affects only its own wave.
// 1-step register prefetch on A hides most of the HBM round trip.
__global__ __launch_bounds__(256, 2) void gemm_tanh_kernel(
    const float* __restrict__ A, const short* __restrict__ Wt,
    unsigned short* __restrict__ H) {
  const int tid = threadIdx.x;
  const int wave = tid >> 6, lane = tid & 63;
  const int quad = lane >> 4, l16 = lane & 15;
  const int R0 = (blockIdx.x * 4 + wave) * 32;

  f32x4 acc[2][16];
  #pragma unroll
  for (int m = 0; m < 2; ++m)
    #pragma unroll
    for (int n = 0; n < 16; ++n) acc[m][n] = (f32x4){0.f, 0.f, 0.f, 0.f};

  // per-lane A fragment bases (quad folded in): row = R0 + m*16 + l16
  const float* Ab0;
  const float* Ab1;
  {
    int g0 = min(R0 + l16, M_NODES - 1);
    int g1 = min(R0 + 16 + l16, M_NODES - 1);
    Ab0 = A + (size_t)g0 * K_IN + quad * 8;
    Ab1 = A + (size_t)g1 * K_IN + quad * 8;
  }
  // per-lane B base: n = nt*16 + l16, k = ks*32 + quad*8 + j
  const short* Bb = Wt + (size_t)l16 * K_IN + quad * 8;

  // ---- prologue: prefetch A fragments for ks=0
  float4 a00 = *(const float4*)(Ab0);
  float4 a01 = *(const float4*)(Ab0 + 4);
  float4 a10 = *(const float4*)(Ab1);
  float4 a11 = *(const float4*)(Ab1 + 4);

  for (int ks = 0; ks < 16; ++ks) {
    // convert prefetched A to bf16 fragments
    bf16x8 af0, af1;
    {
      union { unsigned short s[8]; bf16x8 v; } u;
      u.s[0]=f2bf_u(a00.x); u.s[1]=f2bf_u(a00.y); u.s[2]=f2bf_u(a00.z); u.s[3]=f2bf_u(a00.w);
      u.s[4]=f2bf_u(a01.x); u.s[5]=f2bf_u(a01.y); u.s[6]=f2bf_u(a01.z); u.s[7]=f2bf_u(a01.w);
      af0 = u.v;
      u.s[0]=f2bf_u(a10.x); u.s[1]=f2bf_u(a10.y); u.s[2]=f2bf_u(a10.z); u.s[3]=f2bf_u(a10.w);
      u.s[4]=f2bf_u(a11.x); u.s[5]=f2bf_u(a11.y); u.s[6]=f2bf_u(a11.z); u.s[7]=f2bf_u(a11.w);
      af1 = u.v;
    }
    // issue next-step A loads (independent; retire before next convert)
    if (ks < 15) {
      const float* p0 = Ab0 + (ks + 1) * 32;
      const float* p1 = Ab1 + (ks + 1) * 32;
      a00 = *(const float4*)(p0);
      a01 = *(const float4*)(p0 + 4);
      a10 = *(const float4*)(p1);
      a11 = *(const float4*)(p1 + 4);
    }
    // B loads (L2-hit) + 32 MFMAs
    const short* Bk = Bb + ks * 32;
    #pragma unroll
    for (int nt = 0; nt < 16; ++nt) {
      bf16x8 bfr = *(const bf16x8*)(Bk + (size_t)nt * 16 * K_IN);
      acc[0][nt] = __builtin_amdgcn_mfma_f32_16x16x32_bf16(af0, bfr, acc[0][nt], 0, 0, 0);
      acc[1][nt] = __builtin_amdgcn_mfma_f32_16x16x32_bf16(af1, bfr, acc[1][nt], 0, 0, 0);
    }
  }

  // ---- epilogue: C/D row = R0 + m*16 + quad*4 + rr, col = nt*16 + l16
  #pragma unroll
  for (int m = 0; m < 2; ++m) {
    #pragma unroll
    for (int rr = 0; rr < 4; ++rr) {
      int row = R0 + m * 16 + quad * 4 + rr;
      if (row < M_NODES) {
        #pragma unroll
        for (int nt = 0; nt < 16; ++nt) {
          H[(size_t)row * N_OUT + nt * 16 + l16] =
              f2bf_u(fast_tanh(acc[m][nt][rr]));
        }
      }
    }
  }
}

// y[i,:] = sum_e vals[e]*x[col[e],:], x bf16 [M,256]. One wave/row; lane holds
// 4 features (8B/edge/lane -> full 512B row per edge, coalesced).
// Edge metadata (col/vals) is loaded ONCE per 64-edge chunk as a per-lane
// vector load, then broadcast via __shfl -> the x-row gathers have no
// load->load dependency and are issued 8-deep (MLP=8 per wave).
__global__ __launch_bounds__(256) void spmm_bf_bf(
    const int* __restrict__ rp, const int* __restrict__ colv,
    const float* __restrict__ vals, const unsigned short* __restrict__ x,
    unsigned short* __restrict__ y) {
  int w = (blockIdx.x * 256 + threadIdx.x) >> 6;
  int lane = threadIdx.x & 63;
  int i = __builtin_amdgcn_readfirstlane(w);
  int s = rp[i], e = rp[i + 1];
  float a0 = 0.f, a1 = 0.f, a2 = 0.f, a3 = 0.f;
  const unsigned short* xl = x + lane * 4;
  for (int base = s; base < e; base += 64) {
    int nn = min(e - base, 64);
    int tl = min(base + lane, e - 1);          // clamped: lanes >= nn unused
    int c_l = colv[tl];
    float v_l = vals[tl];
    int tt = 0;
    for (; tt + 8 <= nn; tt += 8) {
      ushort4 xv[8]; float vv[8];
      #pragma unroll
      for (int j = 0; j < 8; ++j) {
        int c = __shfl(c_l, tt + j);
        vv[j] = __shfl(v_l, tt + j);
        xv[j] = *(const ushort4*)(xl + (size_t)c * N_OUT);
      }
      #pragma unroll
      for (int j = 0; j < 8; ++j) {
        a0 += vv[j] * bfu2f(xv[j].x); a1 += vv[j] * bfu2f(xv[j].y);
        a2 += vv[j] * bfu2f(xv[j].z); a3 += vv[j] * bfu2f(xv[j].w);
      }
    }
    for (; tt + 4 <= nn; tt += 4) {
      ushort4 xv[4]; float vv[4];
      #pragma unroll
      for (int j = 0; j < 4; ++j) {
        int c = __shfl(c_l, tt + j);
        vv[j] = __shfl(v_l, tt + j);
        xv[j] = *(const ushort4*)(xl + (size_t)c * N_OUT);
      }
      #pragma unroll
      for (int j = 0; j < 4; ++j) {
        a0 += vv[j] * bfu2f(xv[j].x); a1 += vv[j] * bfu2f(xv[j].y);
        a2 += vv[j] * bfu2f(xv[j].z); a3 += vv[j] * bfu2f(xv[j].w);
      }
    }
    for (; tt < nn; ++tt) {
      int c = __shfl(c_l, tt);
      float v = __shfl(v_l, tt);
      ushort4 xv = *(const ushort4*)(xl + (size_t)c * N_OUT);
      a0 += v * bfu2f(xv.x); a1 += v * bfu2f(xv.y);
      a2 += v * bfu2f(xv.z); a3 += v * bfu2f(xv.w);
    }
  }
  ushort4 o;
  o.x = f2bf_u(a0); o.y = f2bf_u(a1); o.z = f2bf_u(a2); o.w = f2bf_u(a3);
  *(ushort4*)(y + (size_t)i * N_OUT + lane * 4) = o;
}

// same but f32 output (final layer writes d_out)
__global__ __launch_bounds__(256) void spmm_bf_f32(
    const int* __restrict__ rp, const int* __restrict__ colv,
    const float* __restrict__ vals, const unsigned short* __restrict__ x,
    float* __restrict__ y) {
  int w = (blockIdx.x * 256 + threadIdx.x) >> 6;
  int lane = threadIdx.x & 63;
  int i = __builtin_amdgcn_readfirstlane(w);
  int s = rp[i], e = rp[i + 1];
  float a0 = 0.f, a1 = 0.f, a2 = 0.f, a3 = 0.f;
  const unsigned short* xl = x + lane * 4;
  for (int base = s; base < e; base += 64) {
    int nn = min(e - base, 64);
    int tl = min(base + lane, e - 1);
    int c_l = colv[tl];
    float v_l = vals[tl];
    int tt = 0;
    for (; tt + 8 <= nn; tt += 8) {
      ushort4 xv[8]; float vv[8];
      #pragma unroll
      for (int j = 0; j < 8; ++j) {
        int c = __shfl(c_l, tt + j);
        vv[j] = __shfl(v_l, tt + j);
        xv[j] = *(const ushort4*)(xl + (size_t)c * N_OUT);
      }
      #pragma unroll
      for (int j = 0; j < 8; ++j) {
        a0 += vv[j] * bfu2f(xv[j].x); a1 += vv[j] * bfu2f(xv[j].y);
        a2 += vv[j] * bfu2f(xv[j].z); a3 += vv[j] * bfu2f(xv[j].w);
      }
    }
    for (; tt + 4 <= nn; tt += 4) {
      ushort4 xv[4]; float vv[4];
      #pragma unroll
      for (int j = 0; j < 4; ++j) {
        int c = __shfl(c_l, tt + j);
        vv[j] = __shfl(v_l, tt + j);
        xv[j] = *(const ushort4*)(xl + (size_t)c * N_OUT);
      }
      #pragma unroll
      for (int j = 0; j < 4; ++j) {
        a0 += vv[j] * bfu2f(xv[j].x); a1 += vv[j] * bfu2f(xv[j].y);
        a2 += vv[j] * bfu2f(xv[j].z); a3 += vv[j] * bfu2f(xv[j].w);
      }
    }
    for (; tt < nn; ++tt) {
      int c = __shfl(c_l, tt);
      float v = __shfl(v_l, tt);
      ushort4 xv = *(const ushort4*)(xl + (size_t)c * N_OUT);
      a0 += v * bfu2f(xv.x); a1 += v * bfu2f(xv.y);
      a2 += v * bfu2f(xv.z); a3 += v * bfu2f(xv.w);
    }
  }
  float4 o = {a0, a1, a2, a3};
  *(float4*)(y + (size_t)i * N_OUT + lane * 4) = o;
}

extern "C" void kernel_launch(void* const* d_in, const int* in_sizes, int n_in,
                              void* d_out, int out_size, void* d_ws, size_t ws_size,
                              hipStream_t stream) {
  const float* features = (const float*)d_in[0];
  const float* weight   = (const float*)d_in[1];
  const int*   row      = (const int*)d_in[2];
  const int*   col      = (const int*)d_in[3];
  const float* vals     = (const float*)d_in[4];
  float* out = (float*)d_out;

  char* ws = (char*)d_ws;
  const size_t HB = (size_t)M_NODES * N_OUT * 2;   // 51,200,000 bf16 H
  const size_t RPB = 400016;                        // 100001 ints padded
  unsigned short* H  = (unsigned short*)ws;
  unsigned short* y1 = (unsigned short*)(ws + HB);
  int*   rp = (int*)(ws + 2 * HB);
  short* Wt = (short*)(ws + 2 * HB + RPB);
  // total need: 2*51.2MB + 400016 + 262144 = 103,062,160 B (fits)

  prep_w_kernel<<<512, 256, 0, stream>>>(weight, Wt);
  build_rp_kernel<<<(M_NODES + 1 + 255) / 256, 256, 0, stream>>>(row, rp);
  // 4 waves/block, 32 rows/wave -> 128 rows/block
  gemm_tanh_kernel<<<(M_NODES + 127) / 128, 256, 0, stream>>>(features, Wt, H);
  spmm_bf_bf<<<25000, 256, 0, stream>>>(rp, col, vals, H, y1);
  spmm_bf_f32<<<25000, 256, 0, stream>>>(rp, col, vals, y1, out);
}

// Round 4
// 592.860 us; speedup vs baseline: 1.0955x; 1.0955x over previous
//
#include <hip/hip_runtime.h>
#include <hip/hip_bf16.h>

#define M_NODES 100000
#define N_EDGES 1600000
#define K_IN 512
#define N_OUT 256

typedef short bf16x8 __attribute__((ext_vector_type(8)));
typedef float f32x4 __attribute__((ext_vector_type(4)));

__device__ inline unsigned short f2bf_u(float f) {
  union { float f; unsigned u; } x; x.f = f;
  unsigned r = x.u + 0x7FFFu + ((x.u >> 16) & 1u);
  return (unsigned short)(r >> 16);
}
__device__ inline float bfu2f(unsigned short h) {
  union { unsigned u; float f; } x; x.u = ((unsigned)h) << 16;
  return x.f;
}
// tanh(x) = sign(x) * (1-z)/(1+z), z = exp(-2|x|). ~7 VALU + 1 trans.
__device__ inline float fast_tanh(float x) {
  float ax = __builtin_fabsf(x);
  float z = __expf(-2.0f * ax);
  float t = (1.0f - z) * __builtin_amdgcn_rcpf(1.0f + z);
  return __builtin_copysignf(t, x);
}
// pack 8 f32 -> bf16x8 via v_cvt_pk_bf16_f32 (dst.lo = src0, RTNE)
__device__ inline bf16x8 cvt8(float4 lo, float4 hi) {
  union { unsigned u[4]; bf16x8 v; } r;
  asm("v_cvt_pk_bf16_f32 %0, %1, %2" : "=v"(r.u[0]) : "v"(lo.x), "v"(lo.y));
  asm("v_cvt_pk_bf16_f32 %0, %1, %2" : "=v"(r.u[1]) : "v"(lo.z), "v"(lo.w));
  asm("v_cvt_pk_bf16_f32 %0, %1, %2" : "=v"(r.u[2]) : "v"(hi.x), "v"(hi.y));
  asm("v_cvt_pk_bf16_f32 %0, %1, %2" : "=v"(r.u[3]) : "v"(hi.z), "v"(hi.w));
  return r.v;
}

// weight [512][256] f32 -> fragment-major bf16:
// wt[((ks*16+nt)*64 + lane)*8 + j] = bf16(w[ks*32+quad*8+j][nt*16+l16])
// so a wave's B fragment (ks,nt) is 1KB CONTIGUOUS: base + lane*16B.
__global__ void prep_w_kernel(const float* __restrict__ w, short* __restrict__ wt) {
  int frag = blockIdx.x * 256 + threadIdx.x;   // 16384 frags (64 blocks)
  int lane = frag & 63;
  int fi = frag >> 6;                          // ks*16 + nt
  int ks = fi >> 4, nt = fi & 15;
  int quad = lane >> 4, l16 = lane & 15;
  int n = nt * 16 + l16;
  int k0 = ks * 32 + quad * 8;
  #pragma unroll
  for (int j = 0; j < 8; ++j)
    wt[(size_t)frag * 8 + j] = (short)f2bf_u(w[(size_t)(k0 + j) * N_OUT + n]);
}

// row_ptr[r] = lower_bound(row, r) over sorted row[] (COO -> CSR)
__global__ void build_rp_kernel(const int* __restrict__ row, int* __restrict__ rp) {
  int r = blockIdx.x * 256 + threadIdx.x;
  if (r > M_NODES) return;
  int lo = 0, hi = N_EDGES;
  while (lo < hi) {
    int mid = (lo + hi) >> 1;
    if (row[mid] < r) lo = mid + 1; else hi = mid;
  }
  rp[r] = lo;
}

// H = bf16(tanh(A @ W)). Barrier-free, LDS-free, 1 wave per block.
// Wave owns 32 rows x 256 cols (acc 128 f32). 3125 blocks x 32 = 100000
// exactly (no clamps). B from fragment-major Wt (L1/L2-resident, saddr
// loads, zero addr VALU). A from HBM with a 2-kstep register burst.
// vmcnt ORDER DISCIPLINE (in-order retirement!): per kstep-pair the VMEM
// queue is [bP(odd) bQ(odd) | aA' aB' | bP(next-even) bQ(next-even)] --
// every B-wait has no unretired older A in front of it; the HBM latency
// is paid ONCE per pair at the aA' conv. sched_barrier(0) brackets the
// A-burst so the scheduler cannot hoist/sink loads across it.
__global__ __launch_bounds__(64, 2) void gemm_tanh_kernel(
    const float* __restrict__ A, const short* __restrict__ WtF,
    unsigned short* __restrict__ H) {
  const int lane = threadIdx.x;
  const int quad = lane >> 4, l16 = lane & 15;
  const int R0 = blockIdx.x * 32;

  f32x4 acc0[16], acc1[16];   // m=0 rows R0..R0+15 ; m=1 rows R0+16..R0+31
  #pragma unroll
  for (int i = 0; i < 16; ++i) {
    acc0[i] = (f32x4){0.f, 0.f, 0.f, 0.f};
    acc1[i] = (f32x4){0.f, 0.f, 0.f, 0.f};
  }

  const float* Ab0 = A + (size_t)(R0 + l16) * K_IN + quad * 8;
  const float* Ab1 = Ab0 + (size_t)16 * K_IN;
  const short* Bb = WtF + lane * 8;   // + fi*512 shorts per fragment

  float4 aA[4], aB[4];   // A for even/odd kstep of current pair
  bf16x8 bP[8], bQ[8];   // B halves (nt 0..7 / 8..15) of current kstep

  // ---- prologue. queue: [aA aB bP(0) bQ(0)]
  aA[0] = *(const float4*)(Ab0);      aA[1] = *(const float4*)(Ab0 + 4);
  aA[2] = *(const float4*)(Ab1);      aA[3] = *(const float4*)(Ab1 + 4);
  aB[0] = *(const float4*)(Ab0 + 32); aB[1] = *(const float4*)(Ab0 + 36);
  aB[2] = *(const float4*)(Ab1 + 32); aB[3] = *(const float4*)(Ab1 + 36);
  #pragma unroll
  for (int nt = 0; nt < 8; ++nt)
    bP[nt] = *(const bf16x8*)(Bb + (size_t)nt * 512);
  #pragma unroll
  for (int nt = 0; nt < 8; ++nt)
    bQ[nt] = *(const bf16x8*)(Bb + (size_t)(8 + nt) * 512);

  #pragma unroll
  for (int p = 0; p < 8; ++p) {
    const int ks1 = 2 * p + 1;
    // -- even kstep: conv (waits aA = once-per-pair HBM stall)
    bf16x8 af0 = cvt8(aA[0], aA[1]);
    bf16x8 af1 = cvt8(aA[2], aA[3]);
    #pragma unroll
    for (int nt = 0; nt < 8; ++nt) {
      acc0[nt] = __builtin_amdgcn_mfma_f32_16x16x32_bf16(af0, bP[nt], acc0[nt], 0, 0, 0);
      acc1[nt] = __builtin_amdgcn_mfma_f32_16x16x32_bf16(af1, bP[nt], acc1[nt], 0, 0, 0);
    }
    #pragma unroll
    for (int nt = 0; nt < 8; ++nt)   // refill bP <- B(ks1, nt 0..7)
      bP[nt] = *(const bf16x8*)(Bb + (size_t)(ks1 * 16 + nt) * 512);
    #pragma unroll
    for (int nt = 0; nt < 8; ++nt) {
      acc0[8 + nt] = __builtin_amdgcn_mfma_f32_16x16x32_bf16(af0, bQ[nt], acc0[8 + nt], 0, 0, 0);
      acc1[8 + nt] = __builtin_amdgcn_mfma_f32_16x16x32_bf16(af1, bQ[nt], acc1[8 + nt], 0, 0, 0);
    }
    #pragma unroll
    for (int nt = 0; nt < 8; ++nt)   // refill bQ <- B(ks1, nt 8..15)
      bQ[nt] = *(const bf16x8*)(Bb + (size_t)(ks1 * 16 + 8 + nt) * 512);
    // -- odd kstep conv (aB arrived together with aA)
    bf16x8 ag0 = cvt8(aB[0], aB[1]);
    bf16x8 ag1 = cvt8(aB[2], aB[3]);
    // -- A burst for next pair (AFTER this pair's B, BEFORE next-even B)
    if (p < 7) {
      __builtin_amdgcn_sched_barrier(0);
      const float* pa0 = Ab0 + (2 * p + 2) * 32;
      const float* pa1 = Ab1 + (2 * p + 2) * 32;
      aA[0] = *(const float4*)(pa0);      aA[1] = *(const float4*)(pa0 + 4);
      aA[2] = *(const float4*)(pa1);      aA[3] = *(const float4*)(pa1 + 4);
      aB[0] = *(const float4*)(pa0 + 32); aB[1] = *(const float4*)(pa0 + 36);
      aB[2] = *(const float4*)(pa1 + 32); aB[3] = *(const float4*)(pa1 + 36);
      __builtin_amdgcn_sched_barrier(0);
    }
    // -- odd kstep MFMAs
    #pragma unroll
    for (int nt = 0; nt < 8; ++nt) {
      acc0[nt] = __builtin_amdgcn_mfma_f32_16x16x32_bf16(ag0, bP[nt], acc0[nt], 0, 0, 0);
      acc1[nt] = __builtin_amdgcn_mfma_f32_16x16x32_bf16(ag1, bP[nt], acc1[nt], 0, 0, 0);
    }
    #pragma unroll
    for (int nt = 0; nt < 8; ++nt) {
      acc0[8 + nt] = __builtin_amdgcn_mfma_f32_16x16x32_bf16(ag0, bQ[nt], acc0[8 + nt], 0, 0, 0);
      acc1[8 + nt] = __builtin_amdgcn_mfma_f32_16x16x32_bf16(ag1, bQ[nt], acc1[8 + nt], 0, 0, 0);
    }
    // -- refill bP/bQ for next even kstep (issued AFTER the A burst)
    if (p < 7) {
      #pragma unroll
      for (int nt = 0; nt < 8; ++nt)
        bP[nt] = *(const bf16x8*)(Bb + (size_t)((ks1 + 1) * 16 + nt) * 512);
      #pragma unroll
      for (int nt = 0; nt < 8; ++nt)
        bQ[nt] = *(const bf16x8*)(Bb + (size_t)((ks1 + 1) * 16 + 8 + nt) * 512);
    }
  }

  // ---- epilogue: row = R0 + m*16 + quad*4 + rr, col = nt*16 + l16
  #pragma unroll
  for (int nt = 0; nt < 16; ++nt) {
    #pragma unroll
    for (int rr = 0; rr < 4; ++rr) {
      int r0 = R0 + quad * 4 + rr;
      H[(size_t)r0 * N_OUT + nt * 16 + l16] = f2bf_u(fast_tanh(acc0[nt][rr]));
      H[(size_t)(r0 + 16) * N_OUT + nt * 16 + l16] = f2bf_u(fast_tanh(acc1[nt][rr]));
    }
  }
}

// y[i,:] = sum_e vals[e]*x[col[e],:], x bf16 [M,256]. One wave/row; lane holds
// 4 features (8B/edge/lane -> full 512B row per edge, coalesced).
// Edge metadata (col/vals) is loaded ONCE per 64-edge chunk as a per-lane
// vector load, then broadcast via __shfl -> the x-row gathers have no
// load->load dependency and are issued 8-deep (MLP=8 per wave).
__global__ __launch_bounds__(256) void spmm_bf_bf(
    const int* __restrict__ rp, const int* __restrict__ colv,
    const float* __restrict__ vals, const unsigned short* __restrict__ x,
    unsigned short* __restrict__ y) {
  int w = (blockIdx.x * 256 + threadIdx.x) >> 6;
  int lane = threadIdx.x & 63;
  int i = __builtin_amdgcn_readfirstlane(w);
  int s = rp[i], e = rp[i + 1];
  float a0 = 0.f, a1 = 0.f, a2 = 0.f, a3 = 0.f;
  const unsigned short* xl = x + lane * 4;
  for (int base = s; base < e; base += 64) {
    int nn = min(e - base, 64);
    int tl = min(base + lane, e - 1);          // clamped: lanes >= nn unused
    int c_l = colv[tl];
    float v_l = vals[tl];
    int tt = 0;
    for (; tt + 8 <= nn; tt += 8) {
      ushort4 xv[8]; float vv[8];
      #pragma unroll
      for (int j = 0; j < 8; ++j) {
        int c = __shfl(c_l, tt + j);
        vv[j] = __shfl(v_l, tt + j);
        xv[j] = *(const ushort4*)(xl + (size_t)c * N_OUT);
      }
      #pragma unroll
      for (int j = 0; j < 8; ++j) {
        a0 += vv[j] * bfu2f(xv[j].x); a1 += vv[j] * bfu2f(xv[j].y);
        a2 += vv[j] * bfu2f(xv[j].z); a3 += vv[j] * bfu2f(xv[j].w);
      }
    }
    for (; tt + 4 <= nn; tt += 4) {
      ushort4 xv[4]; float vv[4];
      #pragma unroll
      for (int j = 0; j < 4; ++j) {
        int c = __shfl(c_l, tt + j);
        vv[j] = __shfl(v_l, tt + j);
        xv[j] = *(const ushort4*)(xl + (size_t)c * N_OUT);
      }
      #pragma unroll
      for (int j = 0; j < 4; ++j) {
        a0 += vv[j] * bfu2f(xv[j].x); a1 += vv[j] * bfu2f(xv[j].y);
        a2 += vv[j] * bfu2f(xv[j].z); a3 += vv[j] * bfu2f(xv[j].w);
      }
    }
    for (; tt < nn; ++tt) {
      int c = __shfl(c_l, tt);
      float v = __shfl(v_l, tt);
      ushort4 xv = *(const ushort4*)(xl + (size_t)c * N_OUT);
      a0 += v * bfu2f(xv.x); a1 += v * bfu2f(xv.y);
      a2 += v * bfu2f(xv.z); a3 += v * bfu2f(xv.w);
    }
  }
  ushort4 o;
  o.x = f2bf_u(a0); o.y = f2bf_u(a1); o.z = f2bf_u(a2); o.w = f2bf_u(a3);
  *(ushort4*)(y + (size_t)i * N_OUT + lane * 4) = o;
}

// same but f32 output (final layer writes d_out)
__global__ __launch_bounds__(256) void spmm_bf_f32(
    const int* __restrict__ rp, const int* __restrict__ colv,
    const float* __restrict__ vals, const unsigned short* __restrict__ x,
    float* __restrict__ y) {
  int w = (blockIdx.x * 256 + threadIdx.x) >> 6;
  int lane = threadIdx.x & 63;
  int i = __builtin_amdgcn_readfirstlane(w);
  int s = rp[i], e = rp[i + 1];
  float a0 = 0.f, a1 = 0.f, a2 = 0.f, a3 = 0.f;
  const unsigned short* xl = x + lane * 4;
  for (int base = s; base < e; base += 64) {
    int nn = min(e - base, 64);
    int tl = min(base + lane, e - 1);
    int c_l = colv[tl];
    float v_l = vals[tl];
    int tt = 0;
    for (; tt + 8 <= nn; tt += 8) {
      ushort4 xv[8]; float vv[8];
      #pragma unroll
      for (int j = 0; j < 8; ++j) {
        int c = __shfl(c_l, tt + j);
        vv[j] = __shfl(v_l, tt + j);
        xv[j] = *(const ushort4*)(xl + (size_t)c * N_OUT);
      }
      #pragma unroll
      for (int j = 0; j < 8; ++j) {
        a0 += vv[j] * bfu2f(xv[j].x); a1 += vv[j] * bfu2f(xv[j].y);
        a2 += vv[j] * bfu2f(xv[j].z); a3 += vv[j] * bfu2f(xv[j].w);
      }
    }
    for (; tt + 4 <= nn; tt += 4) {
      ushort4 xv[4]; float vv[4];
      #pragma unroll
      for (int j = 0; j < 4; ++j) {
        int c = __shfl(c_l, tt + j);
        vv[j] = __shfl(v_l, tt + j);
        xv[j] = *(const ushort4*)(xl + (size_t)c * N_OUT);
      }
      #pragma unroll
      for (int j = 0; j < 4; ++j) {
        a0 += vv[j] * bfu2f(xv[j].x); a1 += vv[j] * bfu2f(xv[j].y);
        a2 += vv[j] * bfu2f(xv[j].z); a3 += vv[j] * bfu2f(xv[j].w);
      }
    }
    for (; tt < nn; ++tt) {
      int c = __shfl(c_l, tt);
      float v = __shfl(v_l, tt);
      ushort4 xv = *(const ushort4*)(xl + (size_t)c * N_OUT);
      a0 += v * bfu2f(xv.x); a1 += v * bfu2f(xv.y);
      a2 += v * bfu2f(xv.z); a3 += v * bfu2f(xv.w);
    }
  }
  float4 o = {a0, a1, a2, a3};
  *(float4*)(y + (size_t)i * N_OUT + lane * 4) = o;
}

extern "C" void kernel_launch(void* const* d_in, const int* in_sizes, int n_in,
                              void* d_out, int out_size, void* d_ws, size_t ws_size,
                              hipStream_t stream) {
  const float* features = (const float*)d_in[0];
  const float* weight   = (const float*)d_in[1];
  const int*   row      = (const int*)d_in[2];
  const int*   col      = (const int*)d_in[3];
  const float* vals     = (const float*)d_in[4];
  float* out = (float*)d_out;

  char* ws = (char*)d_ws;
  const size_t HB = (size_t)M_NODES * N_OUT * 2;   // 51,200,000 bf16 H
  const size_t RPB = 400016;                        // 100001 ints padded
  unsigned short* H  = (unsigned short*)ws;
  unsigned short* y1 = (unsigned short*)(ws + HB);
  int*   rp = (int*)(ws + 2 * HB);
  short* Wt = (short*)(ws + 2 * HB + RPB);
  // total need: 2*51.2MB + 400016 + 262144 = 103,062,160 B (fits)

  prep_w_kernel<<<64, 256, 0, stream>>>(weight, Wt);
  build_rp_kernel<<<(M_NODES + 1 + 255) / 256, 256, 0, stream>>>(row, rp);
  // 1 wave/block, 32 rows/wave, 3125*32 = 100000 exactly
  gemm_tanh_kernel<<<3125, 64, 0, stream>>>(features, Wt, H);
  spmm_bf_bf<<<25000, 256, 0, stream>>>(rp, col, vals, H, y1);
  spmm_bf_f32<<<25000, 256, 0, stream>>>(rp, col, vals, y1, out);
}